// Round 3
// baseline (480.164 us; speedup 1.0000x reference)
//
#include <hip/hip_runtime.h>
#include <math.h>

#define NN 8192
#define EE 81920
#define E2C 1310720
#define HSZ (1 << 18)
#define HMASK (HSZ - 1)

__device__ __forceinline__ float wsum(float v) {
#pragma unroll
  for (int m = 32; m > 0; m >>= 1) v += __shfl_xor(v, m, 64);
  return v;
}
__device__ __forceinline__ float lrelu(float x) { return x > 0.f ? x : 0.2f * x; }

// P = embed @ gat_W[0:128], Q = embed @ gat_W[128:256]   (one wave per node)
__global__ __launch_bounds__(256) void k_pq(const float* __restrict__ embed,
                                            const float* __restrict__ gw,
                                            float* __restrict__ P, float* __restrict__ Q) {
  __shared__ float Wl[256 * 64];  // 64 KB, plain layout: 2-way bank alias (free)
  for (int i = threadIdx.x; i < 256 * 64; i += 256) Wl[i] = gw[i];
  __syncthreads();
  int lane = threadIdx.x & 63;
  int n = blockIdx.x * 4 + (threadIdx.x >> 6);
  float h0 = embed[n * 128 + lane];
  float h1 = embed[n * 128 + 64 + lane];
  float p = 0.f, q = 0.f;
#pragma unroll
  for (int k = 0; k < 64; k++) {
    float a = __shfl(h0, k, 64);
    float b = __shfl(h1, k, 64);
    p += a * Wl[k * 64 + lane];
    p += b * Wl[(64 + k) * 64 + lane];
    q += a * Wl[(128 + k) * 64 + lane];
    q += b * Wl[(192 + k) * 64 + lane];
  }
  P[n * 64 + lane] = p;
  Q[n * 64 + lane] = q;
}

// per-edge scalars: a_s = hp@att_src, a_d = hp@att_dst, z = hp@lin_W
__global__ __launch_bounds__(256) void k_asd(const float* __restrict__ P, const float* __restrict__ Q,
                                             const int* __restrict__ row, const int* __restrict__ col,
                                             const float* __restrict__ att_s, const float* __restrict__ att_d,
                                             const float* __restrict__ lin_W,
                                             float* __restrict__ a_s, float* __restrict__ a_d,
                                             float* __restrict__ z) {
  int lane = threadIdx.x & 63;
  int e = blockIdx.x * 4 + (threadIdx.x >> 6);
  int r = row[e], c = col[e];
  float v = P[r * 64 + lane] + Q[c * 64 + lane];
  float s1 = wsum(v * att_s[lane]);
  float s2 = wsum(v * att_d[lane]);
  float s3 = wsum(v * lin_W[lane]);
  if (lane == 0) { a_s[e] = s1; a_d[e] = s2; z[e] = s3; }
}

// edge2-parallel scalar GAT accumulation. dn interleaved: dn[2d]=denom, dn[2d+1]=numer
// so both atomics from one entry hit the SAME 32B sector (halves HBM write-back).
__global__ __launch_bounds__(256) void k_acc(const int* __restrict__ src2, const int* __restrict__ dst2,
                                             const float* __restrict__ a_s, const float* __restrict__ a_d,
                                             const float* __restrict__ z, float* __restrict__ dn) {
  int i = (blockIdx.x * 256 + threadIdx.x) * 2;
  int2 s2v = *(const int2*)&src2[i];
  int2 d2v = *(const int2*)&dst2[i];
  float ea0 = __expf(lrelu(a_s[s2v.x] + a_d[d2v.x]));
  float ea1 = __expf(lrelu(a_s[s2v.y] + a_d[d2v.y]));
  float z0 = z[s2v.x], z1 = z[s2v.y];
  atomicAdd(&dn[2 * d2v.x], ea0);
  atomicAdd(&dn[2 * d2v.x + 1], ea0 * z0);
  atomicAdd(&dn[2 * d2v.y], ea1);
  atomicAdd(&dn[2 * d2v.y + 1], ea1 * z1);
}

// fused: finish softmax (self-loop), linear, concrete gate, then hash-accumulate
// (count, gate-sum) per unique (r,c). hPair interleaved: [2i]=cnt, [2i+1]=gsum.
__global__ __launch_bounds__(256) void k_gate_hash(const int* __restrict__ row, const int* __restrict__ col,
                                                   const float* __restrict__ a_s, const float* __restrict__ a_d,
                                                   const float* __restrict__ z, const float* __restrict__ dn,
                                                   const float* __restrict__ gat_bias, const float* __restrict__ lin_W,
                                                   const float* __restrict__ lin_b, const float* __restrict__ noise,
                                                   const float* __restrict__ tmp,
                                                   int* __restrict__ keys, float* __restrict__ hPair) {
  int lane = threadIdx.x & 63;
  float gb = wsum(gat_bias[lane] * lin_W[lane]);  // broadcast scalar
  int e = blockIdx.x * 256 + threadIdx.x;
  float eself = __expf(lrelu(a_s[e] + a_d[e]));  // softmax shift-invariance: skip segment_max
  float la = (dn[2 * e + 1] + eself * z[e]) / (dn[2 * e] + eself) + gb + lin_b[0];
  float ns = noise[e];
  float g = (logf(ns) - log1pf(-ns) + la) / tmp[0];
  float gate = 1.0f / (1.0f + __expf(-g));

  int key = row[e] * NN + col[e];
  unsigned i = ((unsigned)key * 2654435761u) >> 14 & HMASK;
  while (true) {
    int old = atomicCAS(&keys[i], -1, key);
    if (old == -1 || old == key) break;
    i = (i + 1) & HMASK;
  }
  atomicAdd(&hPair[2 * i], 1.0f);
  atomicAdd(&hPair[2 * i + 1], gate);
}

__device__ __forceinline__ int hfind(const int* __restrict__ keys, int key) {
  unsigned i = ((unsigned)key * 2654435761u) >> 14 & HMASK;
  while (true) {
    int k = keys[i];
    if (k == key) return (int)i;
    if (k == -1) return -1;
    i = (i + 1) & HMASK;
  }
}

// edge_mask -> w = sigmoid(mask); deg accumulation + col-CSR counting.
// dc interleaved: dc[2n]=degsum(float), dc[2n+1]=count(int) — same-sector atomics.
__global__ void k_edge_w(const int* __restrict__ row, const int* __restrict__ col,
                         const int* __restrict__ keys, const float* __restrict__ hPair,
                         float* __restrict__ wE, float* __restrict__ dc) {
  int e = blockIdx.x * blockDim.x + threadIdx.x;
  if (e >= EE) return;
  int r = row[e], c = col[e];
  int s1 = hfind(keys, r * NN + c);  // always present (edge e itself)
  float cv = hPair[2 * s1], g1 = hPair[2 * s1 + 1];
  int s2 = hfind(keys, c * NN + r);
  float g2 = (s2 >= 0) ? hPair[2 * s2 + 1] : 0.f;
  float em = cv * 0.5f * (g1 + g2);  // adj * (S + S^T)/2 at (r,c)
  float w = 1.f / (1.f + __expf(-em));
  wE[e] = w;
  atomicAdd(&dc[2 * c], w);
  atomicAdd((int*)dc + 2 * c + 1, 1);
}

// single-block exclusive scan over strided counts; offsets + cursor copy
__global__ __launch_bounds__(1024) void k_scan(const int* __restrict__ cnt, int stride, int n,
                                               int* __restrict__ offs, int* __restrict__ cur) {
  __shared__ int sd[1024];
  int t = threadIdx.x;
  int C = (n + 1023) >> 10;
  int beg = t * C, end = min(beg + C, n);
  int s = 0;
  for (int i = beg; i < end; i++) s += cnt[(size_t)i * stride];
  sd[t] = s;
  __syncthreads();
  for (int off = 1; off < 1024; off <<= 1) {
    int v = (t >= off) ? sd[t - off] : 0;
    __syncthreads();
    sd[t] += v;
    __syncthreads();
  }
  int run = (t == 0) ? 0 : sd[t - 1];
  for (int i = beg; i < end; i++) {
    offs[i] = run;
    cur[i] = run;
    run += cnt[(size_t)i * stride];
  }
  if (t == 0) offs[n] = sd[1023];
}

// scatter packed (row, wE) into col-CSR so gather has a 1-level load chain
__global__ void k_scatter_col(const int* __restrict__ row, const int* __restrict__ col,
                              const float* __restrict__ wE, int* __restrict__ cur,
                              int2* __restrict__ csrP) {
  int e = blockIdx.x * blockDim.x + threadIdx.x;
  if (e >= EE) return;
  int pos = atomicAdd(&cur[col[e]], 1);
  int2 q;
  q.x = row[e];
  q.y = __float_as_int(wE[e]);
  csrP[pos] = q;
}

// t[n] = (xh[n] + sum_{e: col=n} w_e * xh[row_e]) / (1+degsum[n])   (one wave per node)
__global__ __launch_bounds__(256) void k_gather(const float* __restrict__ xh,
                                                const int* __restrict__ colOffs,
                                                const int2* __restrict__ csrP,
                                                const float* __restrict__ dc,
                                                float* __restrict__ T) {
  int lane = threadIdx.x & 63;
  int n = blockIdx.x * 4 + (threadIdx.x >> 6);
  float a0 = xh[n * 128 + lane], a1 = xh[n * 128 + 64 + lane];
  int off = colOffs[n], end = colOffs[n + 1];
  if (off < end) {
    int2 q = csrP[off];
    for (int i = off + 1; i <= end; i++) {
      int2 qn = (i < end) ? csrP[i] : q;  // prefetch next entry (overlaps gathers)
      float wv = __int_as_float(q.y);
      a0 += wv * xh[q.x * 128 + lane];
      a1 += wv * xh[q.x * 128 + 64 + lane];
      q = qn;
    }
  }
  float inv = 1.f / (1.f + dc[2 * n]);
  T[n * 128 + lane] = a0 * inv;
  T[n * 128 + 64 + lane] = a1 * inv;
}

// out = relu(T @ W), W 128x128 in LDS (64 KB), one wave per node
__global__ __launch_bounds__(256) void k_gemm128(const float* __restrict__ T, const float* __restrict__ W,
                                                 float* __restrict__ out) {
  __shared__ float Wl[128 * 128];
  for (int i = threadIdx.x; i < 128 * 128; i += 256) Wl[i] = W[i];
  __syncthreads();
  int lane = threadIdx.x & 63;
  int n = blockIdx.x * 4 + (threadIdx.x >> 6);
  float t0 = T[n * 128 + lane], t1 = T[n * 128 + 64 + lane];
  float a0 = 0.f, a1 = 0.f;
#pragma unroll
  for (int k = 0; k < 64; k++) {
    float ta = __shfl(t0, k, 64);
    float tb = __shfl(t1, k, 64);
    a0 += ta * Wl[k * 128 + lane];
    a1 += ta * Wl[k * 128 + 64 + lane];
    a0 += tb * Wl[(64 + k) * 128 + lane];
    a1 += tb * Wl[(64 + k) * 128 + 64 + lane];
  }
  out[n * 128 + lane] = fmaxf(a0, 0.f);
  out[n * 128 + 64 + lane] = fmaxf(a1, 0.f);
}

__global__ __launch_bounds__(256) void k_pool(const float* __restrict__ H, float* __restrict__ gvec) {
  int t = threadIdx.x;
  int d = t & 127;
  int h = t >> 7;
  int base = blockIdx.x * 64;
  float s = 0.f;
  for (int n = base + h; n < base + 64; n += 2) s += H[n * 128 + d];
  __shared__ float sd[256];
  sd[t] = s;
  __syncthreads();
  if (h == 0) atomicAdd(&gvec[d], sd[t] + sd[t + 128]);
}

__global__ __launch_bounds__(128) void k_final(const float* __restrict__ gvec, const float* __restrict__ Wc,
                                               float* __restrict__ out) {
  int j = threadIdx.x;
  float gj = gvec[j] * (1.0f / 8192.0f);
  __shared__ float s0[128], s1[128];
  s0[j] = gj * Wc[j * 2 + 0];
  s1[j] = gj * Wc[j * 2 + 1];
  __syncthreads();
  for (int o = 64; o > 0; o >>= 1) {
    if (j < o) {
      s0[j] += s0[j + o];
      s1[j] += s1[j + o];
    }
    __syncthreads();
  }
  if (j == 0) {
    float l0 = s0[0], l1 = s1[0];
    float m = fmaxf(l0, l1);
    float e0 = expf(l0 - m), e1 = expf(l1 - m);
    float inv = 1.f / (e0 + e1);
    out[0] = e0 * inv;
    out[1] = e1 * inv;
  }
}

extern "C" void kernel_launch(void* const* d_in, const int* in_sizes, int n_in,
                              void* d_out, int out_size, void* d_ws, size_t ws_size,
                              hipStream_t stream) {
  const float* x     = (const float*)d_in[0];
  const float* embed = (const float*)d_in[1];
  const float* noise = (const float*)d_in[2];
  const float* tmp   = (const float*)d_in[3];
  const float* gat_W = (const float*)d_in[4];
  const float* att_s = (const float*)d_in[5];
  const float* att_d = (const float*)d_in[6];
  const float* gat_b = (const float*)d_in[7];
  const float* lin_W = (const float*)d_in[8];
  const float* lin_b = (const float*)d_in[9];
  const float* W1    = (const float*)d_in[10];
  const float* W2    = (const float*)d_in[11];
  const float* W3    = (const float*)d_in[12];
  const float* Wc    = (const float*)d_in[13];
  const int* ei      = (const int*)d_in[14];
  const int* nei     = (const int*)d_in[15];
  const int* row = ei;
  const int* col = ei + EE;
  const int* src2 = nei;
  const int* dst2 = nei + E2C;
  float* out = (float*)d_out;

  // workspace layout (4-byte units)
  char* w8 = (char*)d_ws;
  size_t off = 0;
  auto alloc = [&](size_t units) -> void* {
    void* p = w8 + off * 4;
    off += units;
    return p;
  };
  float* a_s      = (float*)alloc(EE);
  float* a_d      = (float*)alloc(EE);
  float* z        = (float*)alloc(EE);
  float* wE       = (float*)alloc(EE);
  float* P        = (float*)alloc(NN * 64);
  float* Q        = (float*)alloc(NN * 64);
  // contiguous zero region:
  float* dc       = (float*)alloc(2 * NN);   // [2n]=degsum (f32), [2n+1]=colCnt (int)
  float* gvec     = (float*)alloc(128);
  float* dn       = (float*)alloc(2 * EE);   // [2e]=denom, [2e+1]=numer
  // no-init region:
  int*   colOffs  = (int*)alloc(NN + 1);
  int*   colCur   = (int*)alloc(NN);
  int2*  csrP     = (int2*)alloc(2 * EE);
  // hash (zeroed separately)
  int*   hKeys    = (int*)alloc(HSZ);
  float* hPair    = (float*)alloc(2 * HSZ);  // [2i]=cnt, [2i+1]=gsum
  float* T        = (float*)alloc(NN * 128);
  float* Hbuf     = (float*)alloc(NN * 128);

  hipMemsetAsync(dc, 0, (size_t)(2 * NN + 128 + 2 * EE) * 4, stream);
  hipMemsetAsync(hKeys, 0xFF, (size_t)HSZ * 4, stream);
  hipMemsetAsync(hPair, 0, (size_t)2 * HSZ * 4, stream);

  k_pq<<<NN / 4, 256, 0, stream>>>(embed, gat_W, P, Q);
  k_asd<<<EE / 4, 256, 0, stream>>>(P, Q, row, col, att_s, att_d, lin_W, a_s, a_d, z);
  k_acc<<<E2C / 512, 256, 0, stream>>>(src2, dst2, a_s, a_d, z, dn);
  k_gate_hash<<<EE / 256, 256, 0, stream>>>(row, col, a_s, a_d, z, dn, gat_b, lin_W,
                                            lin_b, noise, tmp, hKeys, hPair);
  k_edge_w<<<EE / 256, 256, 0, stream>>>(row, col, hKeys, hPair, wE, dc);
  k_scan<<<1, 1024, 0, stream>>>((int*)dc + 1, 2, NN, colOffs, colCur);
  k_scatter_col<<<EE / 256, 256, 0, stream>>>(row, col, wE, colCur, csrP);

  // 3-layer edge-weighted GCN
  k_gather<<<NN / 4, 256, 0, stream>>>(x, colOffs, csrP, dc, T);
  k_gemm128<<<NN / 4, 256, 0, stream>>>(T, W1, Hbuf);
  k_gather<<<NN / 4, 256, 0, stream>>>(Hbuf, colOffs, csrP, dc, T);
  k_gemm128<<<NN / 4, 256, 0, stream>>>(T, W2, Hbuf);
  k_gather<<<NN / 4, 256, 0, stream>>>(Hbuf, colOffs, csrP, dc, T);
  k_gemm128<<<NN / 4, 256, 0, stream>>>(T, W3, Hbuf);

  k_pool<<<NN / 64, 256, 0, stream>>>(Hbuf, gvec);
  k_final<<<1, 128, 0, stream>>>(gvec, Wc, out);
}

// Round 4
// 398.152 us; speedup vs baseline: 1.2060x; 1.2060x over previous
//
#include <hip/hip_runtime.h>
#include <hip/hip_fp16.h>
#include <math.h>

#define NN 8192
#define EE 81920
#define E2C 1310720
#define HSZ (1 << 18)
#define HMASK (HSZ - 1)

__device__ __forceinline__ float wsum(float v) {
#pragma unroll
  for (int m = 32; m > 0; m >>= 1) v += __shfl_xor(v, m, 64);
  return v;
}
__device__ __forceinline__ float lrelu(float x) { return x > 0.f ? x : 0.2f * x; }

__device__ __forceinline__ unsigned packh2(float a, float b) {
  __half2 h = __floats2half2_rn(a, b);  // low=a, high=b
  return *reinterpret_cast<unsigned*>(&h);
}
// one 32-bit packed f16x2 atomic add — halves atomic op count vs 2x f32
__device__ __forceinline__ void atomic_pk_add_f16(unsigned* addr, unsigned data) {
  asm volatile("global_atomic_pk_add_f16 %0, %1, off" :: "v"(addr), "v"(data) : "memory");
}

// combo vectors: cA[i] = gat_W_row_i . att_src, etc (i in [0,256))
__global__ __launch_bounds__(256) void k_combo(const float* __restrict__ gw,
                                               const float* __restrict__ att_s,
                                               const float* __restrict__ att_d,
                                               const float* __restrict__ lin_W,
                                               float* __restrict__ cA, float* __restrict__ cD,
                                               float* __restrict__ cZ) {
  int i = threadIdx.x;
  float sa = 0.f, sd = 0.f, sz = 0.f;
#pragma unroll 8
  for (int k = 0; k < 64; k++) {
    float w = gw[i * 64 + k];
    sa += w * att_s[k];
    sd += w * att_d[k];
    sz += w * lin_W[k];
  }
  cA[i] = sa; cD[i] = sd; cZ[i] = sz;
}

// per-node scalars: pN[n]={embed[n].cA_top, .cD_top, .cZ_top}, qN with bottom halves.
// (a_s/a_d/z are linear in hp => P/Q 64-dim arrays never needed)
__global__ __launch_bounds__(256) void k_nodescal(const float* __restrict__ embed,
                                                  const float* __restrict__ cA,
                                                  const float* __restrict__ cD,
                                                  const float* __restrict__ cZ,
                                                  float4* __restrict__ pN, float4* __restrict__ qN) {
  int lane = threadIdx.x & 63;
  int n = blockIdx.x * 4 + (threadIdx.x >> 6);
  float e0 = embed[n * 128 + lane], e1 = embed[n * 128 + 64 + lane];
  float pA = wsum(e0 * cA[lane] + e1 * cA[64 + lane]);
  float qA = wsum(e0 * cA[128 + lane] + e1 * cA[192 + lane]);
  float pD = wsum(e0 * cD[lane] + e1 * cD[64 + lane]);
  float qD = wsum(e0 * cD[128 + lane] + e1 * cD[192 + lane]);
  float pZ = wsum(e0 * cZ[lane] + e1 * cZ[64 + lane]);
  float qZ = wsum(e0 * cZ[128 + lane] + e1 * cZ[192 + lane]);
  if (lane == 0) pN[n] = make_float4(pA, pD, pZ, 0.f);
  if (lane == 1) qN[n] = make_float4(qA, qD, qZ, 0.f);
}

// per-edge scalars (two 16B gathers) + col-CSR counting
__global__ void k_asd(const int* __restrict__ row, const int* __restrict__ col,
                      const float4* __restrict__ pN, const float4* __restrict__ qN,
                      float2* __restrict__ asz, float* __restrict__ ad, int* __restrict__ dcI) {
  int e = blockIdx.x * 256 + threadIdx.x;
  int r = row[e], c = col[e];
  float4 p = pN[r];
  float4 q = qN[c];
  asz[e] = make_float2(p.x + q.x, p.z + q.z);  // {a_s, z}
  ad[e] = p.y + q.y;
  atomicAdd(&dcI[2 * c + 1], 1);
}

// edge2-parallel scalar GAT accumulation: ONE pk-f16 atomic per entry {denom, numer}
__global__ __launch_bounds__(256) void k_acc(const int* __restrict__ src2, const int* __restrict__ dst2,
                                             const float2* __restrict__ asz, const float* __restrict__ ad,
                                             unsigned* __restrict__ dn) {
  int i = (blockIdx.x * 256 + threadIdx.x) * 4;
  int4 s = *(const int4*)&src2[i];
  int4 d = *(const int4*)&dst2[i];
  float2 s0 = asz[s.x], s1 = asz[s.y], s2 = asz[s.z], s3 = asz[s.w];
  float d0 = ad[d.x], d1 = ad[d.y], d2 = ad[d.z], d3 = ad[d.w];
  float ea0 = __expf(lrelu(s0.x + d0));
  float ea1 = __expf(lrelu(s1.x + d1));
  float ea2 = __expf(lrelu(s2.x + d2));
  float ea3 = __expf(lrelu(s3.x + d3));
  atomic_pk_add_f16(&dn[d.x], packh2(ea0, ea0 * s0.y));
  atomic_pk_add_f16(&dn[d.y], packh2(ea1, ea1 * s1.y));
  atomic_pk_add_f16(&dn[d.z], packh2(ea2, ea2 * s2.y));
  atomic_pk_add_f16(&dn[d.w], packh2(ea3, ea3 * s3.y));
}

// fused: finish softmax (self-loop), linear, concrete gate, hash-accumulate {cnt,gsum} pk-f16
__global__ __launch_bounds__(256) void k_gate_hash(const int* __restrict__ row, const int* __restrict__ col,
                                                   const float2* __restrict__ asz, const float* __restrict__ ad,
                                                   const unsigned* __restrict__ dn,
                                                   const float* __restrict__ gat_bias, const float* __restrict__ lin_W,
                                                   const float* __restrict__ lin_b, const float* __restrict__ noise,
                                                   const float* __restrict__ tmp,
                                                   int* __restrict__ keys, unsigned* __restrict__ hPairU) {
  int lane = threadIdx.x & 63;
  float gb = wsum(gat_bias[lane] * lin_W[lane]);  // broadcast scalar
  int e = blockIdx.x * 256 + threadIdx.x;
  float2 sz = asz[e];
  float adv = ad[e];
  float eself = __expf(lrelu(sz.x + adv));  // softmax shift-invariance: skip segment_max
  __half2 dnv = ((const __half2*)dn)[e];
  float denom = __low2float(dnv), numer = __high2float(dnv);
  float la = (numer + eself * sz.y) / (denom + eself) + gb + lin_b[0];
  float ns = noise[e];
  float g = (logf(ns) - log1pf(-ns) + la) / tmp[0];
  float gate = 1.0f / (1.0f + __expf(-g));

  int key = row[e] * NN + col[e];
  unsigned i = ((unsigned)key * 2654435761u) >> 14 & HMASK;
  while (true) {
    int old = atomicCAS(&keys[i], -1, key);
    if (old == -1 || old == key) break;
    i = (i + 1) & HMASK;
  }
  atomic_pk_add_f16(&hPairU[i], packh2(1.0f, gate));
}

__device__ __forceinline__ int hfind(const int* __restrict__ keys, int key) {
  unsigned i = ((unsigned)key * 2654435761u) >> 14 & HMASK;
  while (true) {
    int k = keys[i];
    if (k == key) return (int)i;
    if (k == -1) return -1;
    i = (i + 1) & HMASK;
  }
}

// edge_mask -> w; degsum atomic; CSR scatter of packed (row, w)
__global__ void k_edge_w(const int* __restrict__ row, const int* __restrict__ col,
                         const int* __restrict__ keys, const unsigned* __restrict__ hPairU,
                         float* __restrict__ dc, int* __restrict__ colCur, int2* __restrict__ csrP) {
  int e = blockIdx.x * 256 + threadIdx.x;
  if (e >= EE) return;
  int r = row[e], c = col[e];
  int s1 = hfind(keys, r * NN + c);  // always present (edge e itself)
  __half2 h1 = ((const __half2*)hPairU)[s1];
  float cv = __low2float(h1), g1 = __high2float(h1);
  int s2 = hfind(keys, c * NN + r);
  float g2 = (s2 >= 0) ? __high2float(((const __half2*)hPairU)[s2]) : 0.f;
  float em = cv * 0.5f * (g1 + g2);  // adj * (S + S^T)/2 at (r,c)
  float w = 1.f / (1.f + __expf(-em));
  atomicAdd(&dc[2 * c], w);
  int pos = atomicAdd(&colCur[c], 1);
  csrP[pos] = make_int2(r, __float_as_int(w));
}

// single-block exclusive scan over strided counts; offsets + cursor copy
__global__ __launch_bounds__(1024) void k_scan(const int* __restrict__ cnt, int stride, int n,
                                               int* __restrict__ offs, int* __restrict__ cur) {
  __shared__ int sd[1024];
  int t = threadIdx.x;
  int C = (n + 1023) >> 10;
  int beg = t * C, end = min(beg + C, n);
  int s = 0;
  for (int i = beg; i < end; i++) s += cnt[(size_t)i * stride];
  sd[t] = s;
  __syncthreads();
  for (int off = 1; off < 1024; off <<= 1) {
    int v = (t >= off) ? sd[t - off] : 0;
    __syncthreads();
    sd[t] += v;
    __syncthreads();
  }
  int run = (t == 0) ? 0 : sd[t - 1];
  for (int i = beg; i < end; i++) {
    offs[i] = run;
    cur[i] = run;
    run += cnt[(size_t)i * stride];
  }
  if (t == 0) offs[n] = sd[1023];
}

// fused GCN layer: gather (overlapped with W LDS staging) + 128x128 shuffle-GEMM + relu
__global__ __launch_bounds__(256) void k_layer(const float* __restrict__ xh,
                                               const int* __restrict__ colOffs,
                                               const int2* __restrict__ csrP,
                                               const float* __restrict__ dc,
                                               const float* __restrict__ W,
                                               float* __restrict__ outH) {
  __shared__ float Wl[128 * 128];
  for (int i = threadIdx.x; i < 128 * 128; i += 256) Wl[i] = W[i];
  // NOTE: no sync yet — W staging overlaps the gather below
  int lane = threadIdx.x & 63;
  int n = blockIdx.x * 4 + (threadIdx.x >> 6);
  float a0 = xh[n * 128 + lane], a1 = xh[n * 128 + 64 + lane];
  int off = colOffs[n], end = colOffs[n + 1];
  for (int i = off; i < end; i++) {
    int2 q = csrP[i];
    float wv = __int_as_float(q.y);
    a0 += wv * xh[q.x * 128 + lane];
    a1 += wv * xh[q.x * 128 + 64 + lane];
  }
  float inv = 1.f / (1.f + dc[2 * n]);
  float t0 = a0 * inv, t1 = a1 * inv;
  __syncthreads();
  float c0 = 0.f, c1 = 0.f;
#pragma unroll
  for (int k = 0; k < 64; k++) {
    float ta = __shfl(t0, k, 64);
    float tb = __shfl(t1, k, 64);
    c0 += ta * Wl[k * 128 + lane];
    c1 += ta * Wl[k * 128 + 64 + lane];
    c0 += tb * Wl[(64 + k) * 128 + lane];
    c1 += tb * Wl[(64 + k) * 128 + 64 + lane];
  }
  outH[n * 128 + lane] = fmaxf(c0, 0.f);
  outH[n * 128 + 64 + lane] = fmaxf(c1, 0.f);
}

__global__ __launch_bounds__(256) void k_pool(const float* __restrict__ H, float* __restrict__ gvec) {
  int t = threadIdx.x;
  int d = t & 127;
  int h = t >> 7;
  int base = blockIdx.x * 64;
  float s = 0.f;
  for (int n = base + h; n < base + 64; n += 2) s += H[n * 128 + d];
  __shared__ float sd[256];
  sd[t] = s;
  __syncthreads();
  if (h == 0) atomicAdd(&gvec[d], sd[t] + sd[t + 128]);
}

__global__ __launch_bounds__(128) void k_final(const float* __restrict__ gvec, const float* __restrict__ Wc,
                                               float* __restrict__ out) {
  int j = threadIdx.x;
  float gj = gvec[j] * (1.0f / 8192.0f);
  __shared__ float s0[128], s1[128];
  s0[j] = gj * Wc[j * 2 + 0];
  s1[j] = gj * Wc[j * 2 + 1];
  __syncthreads();
  for (int o = 64; o > 0; o >>= 1) {
    if (j < o) {
      s0[j] += s0[j + o];
      s1[j] += s1[j + o];
    }
    __syncthreads();
  }
  if (j == 0) {
    float l0 = s0[0], l1 = s1[0];
    float m = fmaxf(l0, l1);
    float e0 = expf(l0 - m), e1 = expf(l1 - m);
    float inv = 1.f / (e0 + e1);
    out[0] = e0 * inv;
    out[1] = e1 * inv;
  }
}

extern "C" void kernel_launch(void* const* d_in, const int* in_sizes, int n_in,
                              void* d_out, int out_size, void* d_ws, size_t ws_size,
                              hipStream_t stream) {
  const float* x     = (const float*)d_in[0];
  const float* embed = (const float*)d_in[1];
  const float* noise = (const float*)d_in[2];
  const float* tmp   = (const float*)d_in[3];
  const float* gat_W = (const float*)d_in[4];
  const float* att_s = (const float*)d_in[5];
  const float* att_d = (const float*)d_in[6];
  const float* gat_b = (const float*)d_in[7];
  const float* lin_W = (const float*)d_in[8];
  const float* lin_b = (const float*)d_in[9];
  const float* W1    = (const float*)d_in[10];
  const float* W2    = (const float*)d_in[11];
  const float* W3    = (const float*)d_in[12];
  const float* Wc    = (const float*)d_in[13];
  const int* ei      = (const int*)d_in[14];
  const int* nei     = (const int*)d_in[15];
  const int* row = ei;
  const int* col = ei + EE;
  const int* src2 = nei;
  const int* dst2 = nei + E2C;
  float* out = (float*)d_out;

  // workspace layout (4-byte units)
  char* w8 = (char*)d_ws;
  size_t off = 0;
  auto alloc = [&](size_t units) -> void* {
    void* p = w8 + off * 4;
    off += units;
    return p;
  };
  float*  cA      = (float*)alloc(256);
  float*  cD      = (float*)alloc(256);
  float*  cZ      = (float*)alloc(256);
  float4* pN      = (float4*)alloc(4 * NN);
  float4* qN      = (float4*)alloc(4 * NN);
  float2* asz     = (float2*)alloc(2 * EE);  // {a_s, z}
  float*  ad      = (float*)alloc(EE);
  // contiguous zero region:
  float*    dc    = (float*)alloc(2 * NN);   // [2n]=degsum (f32), [2n+1]=colCnt (int)
  float*    gvec  = (float*)alloc(128);
  unsigned* dn    = (unsigned*)alloc(EE);    // pk f16 {denom, numer}
  unsigned* hPair = (unsigned*)alloc(HSZ);   // pk f16 {cnt, gsum}
  // no-init region:
  int*    colOffs = (int*)alloc(NN + 1);
  int*    colCur  = (int*)alloc(NN);
  int2*   csrP    = (int2*)alloc(2 * EE);
  int*    hKeys   = (int*)alloc(HSZ);        // 0xFF region
  float*  H1      = (float*)alloc(NN * 128);
  float*  H2      = (float*)alloc(NN * 128);

  hipMemsetAsync(dc, 0, (size_t)(2 * NN + 128 + EE + HSZ) * 4, stream);
  hipMemsetAsync(hKeys, 0xFF, (size_t)HSZ * 4, stream);

  k_combo<<<1, 256, 0, stream>>>(gat_W, att_s, att_d, lin_W, cA, cD, cZ);
  k_nodescal<<<NN / 4, 256, 0, stream>>>(embed, cA, cD, cZ, pN, qN);
  k_asd<<<EE / 256, 256, 0, stream>>>(row, col, pN, qN, asz, ad, (int*)dc);
  k_scan<<<1, 1024, 0, stream>>>((int*)dc + 1, 2, NN, colOffs, colCur);
  k_acc<<<E2C / 1024, 256, 0, stream>>>(src2, dst2, asz, ad, dn);
  k_gate_hash<<<EE / 256, 256, 0, stream>>>(row, col, asz, ad, dn, gat_b, lin_W,
                                            lin_b, noise, tmp, hKeys, hPair);
  k_edge_w<<<EE / 256, 256, 0, stream>>>(row, col, hKeys, hPair, dc, colCur, csrP);

  // 3-layer edge-weighted GCN (gather + GEMM fused)
  k_layer<<<NN / 4, 256, 0, stream>>>(x, colOffs, csrP, dc, W1, H1);
  k_layer<<<NN / 4, 256, 0, stream>>>(H1, colOffs, csrP, dc, W2, H2);
  k_layer<<<NN / 4, 256, 0, stream>>>(H2, colOffs, csrP, dc, W3, H1);

  k_pool<<<NN / 64, 256, 0, stream>>>(H1, gvec);
  k_final<<<1, 128, 0, stream>>>(gvec, Wc, out);
}

// Round 5
// 307.803 us; speedup vs baseline: 1.5600x; 1.2935x over previous
//
#include <hip/hip_runtime.h>
#include <hip/hip_fp16.h>
#include <math.h>

#define NN 8192
#define EE 81920
#define E2C 1310720
#define HSZ (1 << 18)
#define HMASK (HSZ - 1)
#define NBIN 160          // dst >> 9 : 160 bins of 512 edge-nodes
#define BCAP 9216         // Binomial(1.31M,1/160): mean 8192, sigma~90 -> +11 sigma

__device__ __forceinline__ float wsum(float v) {
#pragma unroll
  for (int m = 32; m > 0; m >>= 1) v += __shfl_xor(v, m, 64);
  return v;
}
__device__ __forceinline__ float lrelu(float x) { return x > 0.f ? x : 0.2f * x; }

__device__ __forceinline__ unsigned packh2(float a, float b) {
  __half2 h = __floats2half2_rn(a, b);  // low=a, high=b
  return *reinterpret_cast<unsigned*>(&h);
}
__device__ __forceinline__ void atomic_pk_add_f16(unsigned* addr, unsigned data) {
  asm volatile("global_atomic_pk_add_f16 %0, %1, off" :: "v"(addr), "v"(data) : "memory");
}

// one kernel replaces all memsets: hKeys=-1, hPair=0, colCnt=0, gvec=0, gCur=0
__global__ __launch_bounds__(256) void k_init(int* __restrict__ hKeys, unsigned* __restrict__ hPair,
                                              int* __restrict__ colCnt, float* __restrict__ gvec,
                                              unsigned* __restrict__ gCur) {
  int tid = blockIdx.x * 256 + threadIdx.x;  // grid 1024*256 == HSZ
  hKeys[tid] = -1;
  hPair[tid] = 0u;
  if (tid < NN) colCnt[tid] = 0;
  if (tid < 128) gvec[tid] = 0.f;
  if (tid < NBIN) gCur[tid] = 0u;
}

// combo vectors: cA[i] = gat_W_row_i . att_src, etc (i in [0,256))
__global__ __launch_bounds__(256) void k_combo(const float* __restrict__ gw,
                                               const float* __restrict__ att_s,
                                               const float* __restrict__ att_d,
                                               const float* __restrict__ lin_W,
                                               float* __restrict__ cA, float* __restrict__ cD,
                                               float* __restrict__ cZ) {
  int i = threadIdx.x;
  float sa = 0.f, sd = 0.f, sz = 0.f;
#pragma unroll 8
  for (int k = 0; k < 64; k++) {
    float w = gw[i * 64 + k];
    sa += w * att_s[k];
    sd += w * att_d[k];
    sz += w * lin_W[k];
  }
  cA[i] = sa; cD[i] = sd; cZ[i] = sz;
}

// per-node scalars (a_s/a_d/z are linear in hp => no 64-dim P/Q needed)
__global__ __launch_bounds__(256) void k_nodescal(const float* __restrict__ embed,
                                                  const float* __restrict__ cA,
                                                  const float* __restrict__ cD,
                                                  const float* __restrict__ cZ,
                                                  float4* __restrict__ pN, float4* __restrict__ qN) {
  int lane = threadIdx.x & 63;
  int n = blockIdx.x * 4 + (threadIdx.x >> 6);
  float e0 = embed[n * 128 + lane], e1 = embed[n * 128 + 64 + lane];
  float pA = wsum(e0 * cA[lane] + e1 * cA[64 + lane]);
  float qA = wsum(e0 * cA[128 + lane] + e1 * cA[192 + lane]);
  float pD = wsum(e0 * cD[lane] + e1 * cD[64 + lane]);
  float qD = wsum(e0 * cD[128 + lane] + e1 * cD[192 + lane]);
  float pZ = wsum(e0 * cZ[lane] + e1 * cZ[64 + lane]);
  float qZ = wsum(e0 * cZ[128 + lane] + e1 * cZ[192 + lane]);
  if (lane == 0) pN[n] = make_float4(pA, pD, pZ, 0.f);
  if (lane == 1) qN[n] = make_float4(qA, qD, qZ, 0.f);
}

// per-edge scalars (two 16B gathers) + col-CSR counting
__global__ void k_asd(const int* __restrict__ row, const int* __restrict__ col,
                      const float4* __restrict__ pN, const float4* __restrict__ qN,
                      float2* __restrict__ asz, float* __restrict__ ad, int* __restrict__ colCnt) {
  int e = blockIdx.x * 256 + threadIdx.x;
  int r = row[e], c = col[e];
  float4 p = pN[r];
  float4 q = qN[c];
  asz[e] = make_float2(p.x + q.x, p.z + q.z);  // {a_s, z}
  ad[e] = p.y + q.y;
  atomicAdd(&colCnt[c], 1);
}

// phase A: partition 1.31M edge2 entries into 160 dst-range buckets.
// Global atomics: only 320 blocks x 160 bins reservations (~51K). Payload = plain stores.
__global__ __launch_bounds__(256) void k_part(const int* __restrict__ src2, const int* __restrict__ dst2,
                                              const float2* __restrict__ asz, const float* __restrict__ ad,
                                              unsigned* __restrict__ gCur,
                                              unsigned long long* __restrict__ bucket) {
  __shared__ unsigned hist[NBIN], base[NBIN], lcur[NBIN];
  int t = threadIdx.x;
  if (t < NBIN) { hist[t] = 0u; lcur[t] = 0u; }
  __syncthreads();
  int blockBase = blockIdx.x * 4096;
  int4 dv[4];
#pragma unroll
  for (int j = 0; j < 4; j++) {
    dv[j] = *(const int4*)&dst2[blockBase + j * 1024 + t * 4];
    atomicAdd(&hist[dv[j].x >> 9], 1u);
    atomicAdd(&hist[dv[j].y >> 9], 1u);
    atomicAdd(&hist[dv[j].z >> 9], 1u);
    atomicAdd(&hist[dv[j].w >> 9], 1u);
  }
  __syncthreads();
  if (t < NBIN) base[t] = atomicAdd(&gCur[t], hist[t]);
  __syncthreads();
#pragma unroll
  for (int j = 0; j < 4; j++) {
    int4 sv = *(const int4*)&src2[blockBase + j * 1024 + t * 4];
    int ss[4] = {sv.x, sv.y, sv.z, sv.w};
    int dd[4] = {dv[j].x, dv[j].y, dv[j].z, dv[j].w};
#pragma unroll
    for (int k = 0; k < 4; k++) {
      int s = ss[k], d = dd[k];
      float2 az = asz[s];
      float ea = __expf(lrelu(az.x + ad[d]));
      unsigned pk = packh2(ea, ea * az.y);
      int b = d >> 9;
      unsigned r = atomicAdd(&lcur[b], 1u);
      bucket[(size_t)b * BCAP + base[b] + r] =
          ((unsigned long long)(d & 511) << 32) | pk;
    }
  }
}

// phase B: per-bin LDS segmented reduce -> dn as clean float2 {denom, numer}
__global__ __launch_bounds__(256) void k_reduce(const unsigned long long* __restrict__ bucket,
                                                const unsigned* __restrict__ gCur,
                                                float2* __restrict__ dn) {
  __shared__ float acc[1024];  // 512 dsts x {denom, numer}
  int b = blockIdx.x, t = threadIdx.x;
  for (int i = t; i < 1024; i += 256) acc[i] = 0.f;
  __syncthreads();
  int cnt = (int)gCur[b];
  const unsigned long long* bp = bucket + (size_t)b * BCAP;
  for (int i = t; i < cnt; i += 256) {
    unsigned long long e = bp[i];
    int local = (int)(e >> 32);
    unsigned pk = (unsigned)e;
    __half2 h = *reinterpret_cast<__half2*>(&pk);
    atomicAdd(&acc[2 * local], __low2float(h));
    atomicAdd(&acc[2 * local + 1], __high2float(h));
  }
  __syncthreads();
  for (int i = t; i < 512; i += 256)
    dn[b * 512 + i] = make_float2(acc[2 * i], acc[2 * i + 1]);
}

// fused: finish softmax (self-loop), linear, concrete gate, hash-accumulate {cnt,gsum} pk-f16
__global__ __launch_bounds__(256) void k_gate_hash(const int* __restrict__ row, const int* __restrict__ col,
                                                   const float2* __restrict__ asz, const float* __restrict__ ad,
                                                   const float2* __restrict__ dn,
                                                   const float* __restrict__ gat_bias, const float* __restrict__ lin_W,
                                                   const float* __restrict__ lin_b, const float* __restrict__ noise,
                                                   const float* __restrict__ tmp,
                                                   int* __restrict__ keys, unsigned* __restrict__ hPairU) {
  int lane = threadIdx.x & 63;
  float gb = wsum(gat_bias[lane] * lin_W[lane]);  // broadcast scalar
  int e = blockIdx.x * 256 + threadIdx.x;
  float2 sz = asz[e];
  float eself = __expf(lrelu(sz.x + ad[e]));  // softmax shift-invariance: skip segment_max
  float2 dnv = dn[e];
  float la = (dnv.y + eself * sz.y) / (dnv.x + eself) + gb + lin_b[0];
  float ns = noise[e];
  float g = (logf(ns) - log1pf(-ns) + la) / tmp[0];
  float gate = 1.0f / (1.0f + __expf(-g));

  int key = row[e] * NN + col[e];
  unsigned i = ((unsigned)key * 2654435761u) >> 14 & HMASK;
  while (true) {
    int old = atomicCAS(&keys[i], -1, key);
    if (old == -1 || old == key) break;
    i = (i + 1) & HMASK;
  }
  atomic_pk_add_f16(&hPairU[i], packh2(1.0f, gate));
}

__device__ __forceinline__ int hfind(const int* __restrict__ keys, int key) {
  unsigned i = ((unsigned)key * 2654435761u) >> 14 & HMASK;
  while (true) {
    int k = keys[i];
    if (k == key) return (int)i;
    if (k == -1) return -1;
    i = (i + 1) & HMASK;
  }
}

// edge_mask -> w; CSR scatter of packed (row, w). degsum folded into k_layer's edge walk.
__global__ void k_edge_w(const int* __restrict__ row, const int* __restrict__ col,
                         const int* __restrict__ keys, const unsigned* __restrict__ hPairU,
                         int* __restrict__ colCur, int2* __restrict__ csrP) {
  int e = blockIdx.x * 256 + threadIdx.x;
  if (e >= EE) return;
  int r = row[e], c = col[e];
  int s1 = hfind(keys, r * NN + c);  // always present (edge e itself)
  unsigned u1 = hPairU[s1];
  __half2 h1 = *reinterpret_cast<__half2*>(&u1);
  float cv = __low2float(h1), g1 = __high2float(h1);
  int s2 = hfind(keys, c * NN + r);
  float g2 = 0.f;
  if (s2 >= 0) {
    unsigned u2 = hPairU[s2];
    g2 = __high2float(*reinterpret_cast<__half2*>(&u2));
  }
  float em = cv * 0.5f * (g1 + g2);  // adj * (S + S^T)/2 at (r,c)
  float w = 1.f / (1.f + __expf(-em));
  int pos = atomicAdd(&colCur[c], 1);
  csrP[pos] = make_int2(r, __float_as_int(w));
}

// single-block exclusive scan; offsets + cursor copy
__global__ __launch_bounds__(1024) void k_scan(const int* __restrict__ cnt, int n,
                                               int* __restrict__ offs, int* __restrict__ cur) {
  __shared__ int sd[1024];
  int t = threadIdx.x;
  int C = (n + 1023) >> 10;
  int beg = t * C, end = min(beg + C, n);
  int s = 0;
  for (int i = beg; i < end; i++) s += cnt[i];
  sd[t] = s;
  __syncthreads();
  for (int off = 1; off < 1024; off <<= 1) {
    int v = (t >= off) ? sd[t - off] : 0;
    __syncthreads();
    sd[t] += v;
    __syncthreads();
  }
  int run = (t == 0) ? 0 : sd[t - 1];
  for (int i = beg; i < end; i++) {
    offs[i] = run;
    cur[i] = run;
    run += cnt[i];
  }
  if (t == 0) offs[n] = sd[1023];
}

// fused GCN layer: 16 nodes/block (4 per wave). Gather -> T tile in LDS -> GEMM with
// broadcast T reads (no shfl). degsum computed inline from the edge walk.
__global__ __launch_bounds__(256) void k_layer(const float* __restrict__ xh,
                                               const int* __restrict__ colOffs,
                                               const int2* __restrict__ csrP,
                                               const float* __restrict__ W,
                                               float* __restrict__ outH) {
  __shared__ float Wl[128 * 128];  // 64 KB
  __shared__ float Tl[16 * 128];   // 8 KB
  for (int i = threadIdx.x; i < 4096; i += 256)
    ((float4*)Wl)[i] = ((const float4*)W)[i];
  int lane = threadIdx.x & 63;
  int wv = threadIdx.x >> 6;
  int nb = blockIdx.x * 16;
#pragma unroll
  for (int j = 0; j < 4; j++) {
    int n = nb + wv * 4 + j;
    float a0 = xh[n * 128 + lane], a1 = xh[n * 128 + 64 + lane];
    float ws = 0.f;
    int off = colOffs[n], end = colOffs[n + 1];
    for (int i = off; i < end; i++) {
      int2 q = csrP[i];
      float wgt = __int_as_float(q.y);
      ws += wgt;  // same value in all lanes (uniform load)
      a0 += wgt * xh[q.x * 128 + lane];
      a1 += wgt * xh[q.x * 128 + 64 + lane];
    }
    float inv = 1.f / (1.f + ws);
    Tl[(wv * 4 + j) * 128 + lane] = a0 * inv;
    Tl[(wv * 4 + j) * 128 + 64 + lane] = a1 * inv;
  }
  __syncthreads();
  float2 acc[4];
#pragma unroll
  for (int j = 0; j < 4; j++) acc[j] = make_float2(0.f, 0.f);
  for (int k = 0; k < 128; k += 2) {
    float2 w0 = *(const float2*)&Wl[k * 128 + 2 * lane];
    float2 w1 = *(const float2*)&Wl[(k + 1) * 128 + 2 * lane];
#pragma unroll
    for (int j = 0; j < 4; j++) {
      float2 tv = *(const float2*)&Tl[(wv * 4 + j) * 128 + k];  // broadcast read
      acc[j].x += tv.x * w0.x + tv.y * w1.x;
      acc[j].y += tv.x * w0.y + tv.y * w1.y;
    }
  }
#pragma unroll
  for (int j = 0; j < 4; j++) {
    int n = nb + wv * 4 + j;
    *(float2*)&outH[n * 128 + 2 * lane] =
        make_float2(fmaxf(acc[j].x, 0.f), fmaxf(acc[j].y, 0.f));
  }
}

__global__ __launch_bounds__(256) void k_pool(const float* __restrict__ H, float* __restrict__ gvec) {
  int t = threadIdx.x;
  int d = t & 127;
  int h = t >> 7;
  int base = blockIdx.x * 64;
  float s = 0.f;
  for (int n = base + h; n < base + 64; n += 2) s += H[n * 128 + d];
  __shared__ float sd[256];
  sd[t] = s;
  __syncthreads();
  if (h == 0) atomicAdd(&gvec[d], sd[t] + sd[t + 128]);
}

__global__ __launch_bounds__(128) void k_final(const float* __restrict__ gvec, const float* __restrict__ Wc,
                                               float* __restrict__ out) {
  int j = threadIdx.x;
  float gj = gvec[j] * (1.0f / 8192.0f);
  __shared__ float s0[128], s1[128];
  s0[j] = gj * Wc[j * 2 + 0];
  s1[j] = gj * Wc[j * 2 + 1];
  __syncthreads();
  for (int o = 64; o > 0; o >>= 1) {
    if (j < o) {
      s0[j] += s0[j + o];
      s1[j] += s1[j + o];
    }
    __syncthreads();
  }
  if (j == 0) {
    float l0 = s0[0], l1 = s1[0];
    float m = fmaxf(l0, l1);
    float e0 = expf(l0 - m), e1 = expf(l1 - m);
    float inv = 1.f / (e0 + e1);
    out[0] = e0 * inv;
    out[1] = e1 * inv;
  }
}

extern "C" void kernel_launch(void* const* d_in, const int* in_sizes, int n_in,
                              void* d_out, int out_size, void* d_ws, size_t ws_size,
                              hipStream_t stream) {
  const float* x     = (const float*)d_in[0];
  const float* embed = (const float*)d_in[1];
  const float* noise = (const float*)d_in[2];
  const float* tmp   = (const float*)d_in[3];
  const float* gat_W = (const float*)d_in[4];
  const float* att_s = (const float*)d_in[5];
  const float* att_d = (const float*)d_in[6];
  const float* gat_b = (const float*)d_in[7];
  const float* lin_W = (const float*)d_in[8];
  const float* lin_b = (const float*)d_in[9];
  const float* W1    = (const float*)d_in[10];
  const float* W2    = (const float*)d_in[11];
  const float* W3    = (const float*)d_in[12];
  const float* Wc    = (const float*)d_in[13];
  const int* ei      = (const int*)d_in[14];
  const int* nei     = (const int*)d_in[15];
  const int* row = ei;
  const int* col = ei + EE;
  const int* src2 = nei;
  const int* dst2 = nei + E2C;
  float* out = (float*)d_out;

  // workspace layout (4-byte units); alignment-needy (16B/8B) buffers first
  char* w8 = (char*)d_ws;
  size_t off = 0;
  auto alloc = [&](size_t units) -> void* {
    void* p = w8 + off * 4;
    off += units;
    return p;
  };
  float4* pN    = (float4*)alloc(4 * NN);
  float4* qN    = (float4*)alloc(4 * NN);
  float2* asz   = (float2*)alloc(2 * EE);
  float2* dn    = (float2*)alloc(2 * EE);
  int2*   csrP  = (int2*)alloc(2 * EE);
  unsigned long long* bucket = (unsigned long long*)alloc(2 * (size_t)NBIN * BCAP);
  float*  ad    = (float*)alloc(EE);
  int*    colCnt = (int*)alloc(NN);
  float*  gvec  = (float*)alloc(128);
  unsigned* gCur = (unsigned*)alloc(NBIN + 96);  // pad to even
  int*    colCur = (int*)alloc(NN);
  int*    hKeys = (int*)alloc(HSZ);
  unsigned* hPair = (unsigned*)alloc(HSZ);
  float*  cA    = (float*)alloc(256);
  float*  cD    = (float*)alloc(256);
  float*  cZ    = (float*)alloc(256);
  float*  H1    = (float*)alloc(NN * 128);
  float*  H2    = (float*)alloc(NN * 128);
  int*    colOffs = (int*)alloc(NN + 1);

  k_init<<<HSZ / 256, 256, 0, stream>>>(hKeys, hPair, colCnt, gvec, gCur);
  k_combo<<<1, 256, 0, stream>>>(gat_W, att_s, att_d, lin_W, cA, cD, cZ);
  k_nodescal<<<NN / 4, 256, 0, stream>>>(embed, cA, cD, cZ, pN, qN);
  k_asd<<<EE / 256, 256, 0, stream>>>(row, col, pN, qN, asz, ad, colCnt);
  k_scan<<<1, 1024, 0, stream>>>(colCnt, NN, colOffs, colCur);
  k_part<<<E2C / 4096, 256, 0, stream>>>(src2, dst2, asz, ad, gCur, bucket);
  k_reduce<<<NBIN, 256, 0, stream>>>(bucket, gCur, dn);
  k_gate_hash<<<EE / 256, 256, 0, stream>>>(row, col, asz, ad, dn, gat_b, lin_W,
                                            lin_b, noise, tmp, hKeys, hPair);
  k_edge_w<<<EE / 256, 256, 0, stream>>>(row, col, hKeys, hPair, colCur, csrP);

  // 3-layer edge-weighted GCN (gather + GEMM fused, 16 nodes/block)
  k_layer<<<NN / 16, 256, 0, stream>>>(x, colOffs, csrP, W1, H1);
  k_layer<<<NN / 16, 256, 0, stream>>>(H1, colOffs, csrP, W2, H2);
  k_layer<<<NN / 16, 256, 0, stream>>>(H2, colOffs, csrP, W3, H1);

  k_pool<<<NN / 64, 256, 0, stream>>>(H1, gvec);
  k_final<<<1, 128, 0, stream>>>(gvec, Wc, out);
}